// Round 8
// baseline (329.682 us; speedup 1.0000x reference)
//
#include <hip/hip_runtime.h>

typedef unsigned int uint;
typedef __attribute__((ext_vector_type(8))) short bf16x8;
typedef __attribute__((ext_vector_type(4))) float f32x4;

#define D_IN 128
#define D_H  128
#define D_OUT 16
#define NPC 512                // nodes per coarse bucket
#define NPCSH 9
#define CLDS 224               // >= C = ceil(N/NPC) = 196
#define P1 256                 // pass-1 blocks
#define XL_STRIDE 68
#define WT_STRIDE 68

static __device__ __forceinline__ float bflo(uint u) { return __uint_as_float(u << 16); }
static __device__ __forceinline__ float bfhi(uint u) { return __uint_as_float(u & 0xFFFF0000u); }
static __device__ __forceinline__ uint f2bf(float f) {
    uint b = __float_as_uint(f);
    return (b + 0x7FFFu + ((b >> 16) & 1u)) >> 16;  // RNE
}
static __device__ __forceinline__ uint pk(float a, float b) {
    return f2bf(a) | (f2bf(b) << 16);
}

// ---- pass 1: coarse histogram + W1 pre-pack + deg zeroing ------------------
// blocks [0,P1): histogram (hist1 TRANSPOSED: hist1[bucket*P1 + block]) and
//               zero a chunk of deg (ready before p1fill's atomics).
// blocks [P1,P1+32): pack W1 -> W1p[k2*128+f] = pk(W1[2k2][f], W1[2k2+1][f]).

__global__ __launch_bounds__(256) void k_p1hist(const int* __restrict__ dst, int E, int N, int C,
                                                int chunk, int* __restrict__ hist1,
                                                const float* __restrict__ W1,
                                                uint* __restrict__ W1p,
                                                int* __restrict__ deg) {
    __shared__ int h[CLDS];
    int t = threadIdx.x, b = blockIdx.x;
    if (b >= P1) {  // W1 pack role
        int p = (b - P1) * 256 + t;  // 32*256 = 8192 = 64*128
        int k2 = p >> 7, f = p & 127;
        float w0 = W1[(size_t)(2 * k2) * 128 + f];
        float w1 = W1[(size_t)(2 * k2 + 1) * 128 + f];
        W1p[p] = pk(w0, w1);
        return;
    }
    // zero this block's chunk of deg (p1fill accumulates into it next dispatch)
    int chunkN = (N + P1 - 1) / P1;
    int n0 = b * chunkN, n1 = min(n0 + chunkN, N);
    for (int i = n0 + t; i < n1; i += 256) deg[i] = 0;
    for (int i = t; i < C; i += 256) h[i] = 0;
    __syncthreads();
    int e0 = b * chunk, e1 = min(e0 + chunk, E);
    for (int e = e0 + t; e < e1; e += 256) {
        int d = dst[e];
        d = max(0, min(d, N - 1));
        atomicAdd(&h[d >> NPCSH], 1);
    }
    __syncthreads();
    for (int i = t; i < C; i += 256) hist1[(size_t)i * P1 + b] = h[i];
}

// wave-parallel: per-bucket wave scan (int4/lane over 256 counts) -> local
// prefixes; block scan over bucket totals -> cbase; add base back per bucket.
__global__ __launch_bounds__(1024) void k_p1scan(int* __restrict__ hist1, int C,
                                                 int* __restrict__ cbase) {
    __shared__ int col[CLDS];
    __shared__ int sdata[1024];
    int t = threadIdx.x;
    int w = t >> 6, lane = t & 63;
    // Phase A: each wave scans whole buckets (coalesced int4 loads)
    for (int i = w; i < C; i += 16) {
        int4 v = ((const int4*)hist1)[i * 64 + lane];
        int s = v.x + v.y + v.z + v.w;
        int inc = s;
        for (int off = 1; off < 64; off <<= 1) {
            int o = __shfl_up(inc, off);
            if (lane >= off) inc += o;
        }
        int excl = inc - s;
        int4 p;
        p.x = excl;
        p.y = excl + v.x;
        p.z = excl + v.x + v.y;
        p.w = excl + v.x + v.y + v.z;
        ((int4*)hist1)[i * 64 + lane] = p;  // local (bucket-relative) cursors
        if (lane == 63) col[i] = inc;       // bucket total
    }
    __syncthreads();
    // Phase B: block scan over C bucket totals
    int v = (t < C) ? col[t] : 0;
    sdata[t] = v;
    __syncthreads();
    for (int off = 1; off < 1024; off <<= 1) {
        int x = (t >= off) ? sdata[t - off] : 0;
        __syncthreads();
        sdata[t] += x;
        __syncthreads();
    }
    int pos = sdata[t] - v;  // exclusive
    if (t < C) cbase[t] = pos;
    if (t == 1023) cbase[C] = sdata[1023];
    if (t < C) col[t] = pos;  // bucket base for phase C
    __syncthreads();
    // Phase C: same wave owns same buckets -> add bucket base to local cursors
    for (int i = w; i < C; i += 16) {
        int base = col[i];
        int4 p = ((int4*)hist1)[i * 64 + lane];
        p.x += base; p.y += base; p.z += base; p.w += base;
        ((int4*)hist1)[i * 64 + lane] = p;
    }
}

// scatter packed (dst_local_coarse<<17 | src) into coarse regions, LDS cursors
// only; ALSO accumulates per-node degree via global atomics (deg zeroed by
// k_p1hist) -- this removes the serial k_deg dispatch (R7 cost ~20us wall).
__global__ __launch_bounds__(256) void k_p1fill(const int* __restrict__ src,
                                                const int* __restrict__ dst, int E, int N, int C,
                                                int chunk, const int* __restrict__ hist1,
                                                uint* __restrict__ binned1,
                                                int* __restrict__ deg) {
    __shared__ int cur[CLDS];
    int t = threadIdx.x, b = blockIdx.x;
    for (int i = t; i < C; i += 256) cur[i] = hist1[(size_t)i * P1 + b];
    __syncthreads();
    int e0 = b * chunk, e1 = min(e0 + chunk, E);
    for (int e = e0 + t; e < e1; e += 256) {
        int d = dst[e];
        d = max(0, min(d, N - 1));
        int s = src[e];
        s = max(0, min(s, N - 1));
        int p = atomicAdd(&cur[d >> NPCSH], 1);
        binned1[p] = ((uint)(d & (NPC - 1)) << 17) | (uint)s;
        atomicAdd(&deg[d], 1);
    }
}

// ---- fused: p2 (fine CSR sort) PARALLEL WITH gemm1 (MFMA, persistent) ------
// blocks [0,C): p2 role -- rowptr + sorted ssrc (deg from p1fill atomics).
// blocks [C, C+768): gemm1 role -- hs_b = bf16( dinv[i] * (x @ W1) ), dinv
// computed on the fly as rsqrtf(deg+1): deg is ready (p1fill completed).

__global__ __launch_bounds__(256) void k_p2gemm1(const uint* __restrict__ binned1,
                                                 const int* __restrict__ cbase, int N, int C,
                                                 int* __restrict__ ssrc, int* __restrict__ rowptr,
                                                 const int* __restrict__ deg,
                                                 const uint* __restrict__ W1p,
                                                 const float* __restrict__ x,
                                                 uint* __restrict__ hs_b, int ntiles) {
    __shared__ uint smem[128 * WT_STRIDE + 64 * XL_STRIDE];  // 52224 B
    int t = threadIdx.x;
    if ((int)blockIdx.x < C) {
        // ---------------- p2 role ----------------
        int* ncnt = (int*)smem;
        int* nbase_ = ncnt + NPC;
        int* sdata = nbase_ + NPC;
        int c = blockIdx.x;
        int start = cbase[c], end = cbase[c + 1];
        for (int i = t; i < NPC; i += 256) ncnt[i] = 0;
        __syncthreads();
        for (int j = start + t; j < end; j += 256) atomicAdd(&ncnt[binned1[j] >> 17], 1);
        __syncthreads();
        // parallel exclusive scan, 2 elements per thread (order-preserving)
        int v0 = ncnt[2 * t], v1 = ncnt[2 * t + 1];
        int s = v0 + v1;
        sdata[t] = s;
        __syncthreads();
        for (int off = 1; off < 256; off <<= 1) {
            int xv = (t >= off) ? sdata[t - off] : 0;
            __syncthreads();
            sdata[t] += xv;
            __syncthreads();
        }
        int pre = sdata[t] - s;
        nbase_[2 * t] = start + pre;
        nbase_[2 * t + 1] = start + pre + v0;
        __syncthreads();
        for (int i = t; i < NPC; i += 256) {
            int node = c * NPC + i;
            if (node < N) rowptr[node] = nbase_[i];
        }
        __syncthreads();
        for (int i = t; i < NPC; i += 256) ncnt[i] = nbase_[i];  // reuse as cursors
        __syncthreads();
        for (int j = start + t; j < end; j += 256) {
            uint pe = binned1[j];
            int p = atomicAdd(&ncnt[pe >> 17], 1);
            ssrc[p] = (int)(pe & 0x1FFFFu);
        }
        return;
    }
    // ---------------- gemm1 role ----------------
    uint* Wt = smem;                        // [f][k2] bf16 pairs
    uint* xl = smem + 128 * WT_STRIDE;      // [row][k2] bf16 pairs; reused as out
    int role = blockIdx.x - C;
    int nroles = gridDim.x - C;
    for (int p = t; p < 64 * 128; p += 256) {
        int k2 = p >> 7, f = p & 127;
        Wt[f * WT_STRIDE + k2] = W1p[p];
    }
    int w = t >> 6, lane = t & 63;
    int q = lane >> 4, m = lane & 15;
    const float4* x4 = (const float4*)x;
    for (int tile = role; tile < ntiles; tile += nroles) {
        int row0 = tile * 64;
        __syncthreads();  // Wt ready (iter 0) / outl fully drained (iters > 0)
        for (int p = t; p < 64 * 32; p += 256) {
            int r = p >> 5, c2 = p & 31;
            int gr = row0 + r;
            float4 v = (gr < N) ? x4[(size_t)gr * 32 + c2] : make_float4(0.f, 0.f, 0.f, 0.f);
            *(uint2*)&xl[r * XL_STRIDE + 2 * c2] = make_uint2(pk(v.x, v.y), pk(v.z, v.w));
        }
        __syncthreads();
        // preload all A fragments (xl dead afterwards)
        bf16x8 afr[4][4];
#pragma unroll
        for (int rt = 0; rt < 4; rt++)
#pragma unroll
            for (int kc = 0; kc < 4; kc++)
                afr[rt][kc] = *(const bf16x8*)&xl[(rt * 16 + m) * XL_STRIDE + kc * 16 + q * 4];
        f32x4 acc[2][4];
#pragma unroll
        for (int c = 0; c < 2; c++)
#pragma unroll
            for (int rt = 0; rt < 4; rt++) acc[c][rt] = (f32x4){0.f, 0.f, 0.f, 0.f};
#pragma unroll
        for (int c = 0; c < 2; c++) {
            int f = w * 32 + c * 16 + m;
#pragma unroll
            for (int kc = 0; kc < 4; kc++) {
                bf16x8 bfr = *(const bf16x8*)&Wt[f * WT_STRIDE + kc * 16 + q * 4];
#pragma unroll
                for (int rt = 0; rt < 4; rt++)
                    acc[c][rt] = __builtin_amdgcn_mfma_f32_16x16x32_bf16(afr[rt][kc], bfr,
                                                                         acc[c][rt], 0, 0, 0);
            }
        }
        __syncthreads();  // all waves done reading xl
        uint* outl = xl;  // 64 x 65 packed out tile
#pragma unroll
        for (int rt = 0; rt < 4; rt++) {
            int gb = row0 + rt * 16 + q * 4;
            float dr[4];
            if (gb + 3 < N) {
                int4 dv = *(const int4*)&deg[gb];
                dr[0] = rsqrtf((float)dv.x + 1.0f);
                dr[1] = rsqrtf((float)dv.y + 1.0f);
                dr[2] = rsqrtf((float)dv.z + 1.0f);
                dr[3] = rsqrtf((float)dv.w + 1.0f);
            } else {
#pragma unroll
                for (int r = 0; r < 4; r++)
                    dr[r] = (gb + r < N) ? rsqrtf((float)deg[gb + r] + 1.0f) : 0.f;
            }
#pragma unroll
            for (int c = 0; c < 2; c++) {
                f32x4 a = acc[c][rt];
#pragma unroll
                for (int r = 0; r < 4; r++) {
                    float v = a[r] * dr[r];  // PRE-SCALED by dinv[row]
                    float vn = __shfl_xor(v, 1);
                    if (!(lane & 1)) {
                        int row = rt * 16 + q * 4 + r;
                        int cp = (w * 32 + c * 16 + m) >> 1;
                        outl[row * 65 + cp] = pk(v, vn);
                    }
                }
            }
        }
        __syncthreads();
        for (int p = t; p < 64 * 64; p += 256) {
            int r = p >> 6, cc = p & 63;
            int gr = row0 + r;
            if (gr < N) hs_b[(size_t)gr * 64 + cc] = outl[r * 65 + cc];
        }
    }
}

// ---- AGG1: wave per node, gather-sum PRE-SCALED bf16 rows (proven 66us) ----
// dinv computed on the fly from deg (already loaded); no dinv array.

__global__ __launch_bounds__(256) void k_agg1(const uint* __restrict__ hs_b,
                                              const int* __restrict__ rowptr,
                                              const int* __restrict__ deg,
                                              const int* __restrict__ ssrc,
                                              const float2* __restrict__ b1, int N,
                                              uint* __restrict__ rh_b) {
    int w = threadIdx.x >> 6, lane = threadIdx.x & 63;
    int d = blockIdx.x * 4 + w;
    if (d >= N) return;
    int start = rowptr[d], cnt = deg[d];
    uint sv = hs_b[(size_t)d * 64 + lane];  // self-loop (pre-scaled)
    float a0 = bflo(sv), a1 = bfhi(sv);
    int base = 0;
    while (base < cnt) {
        int nb = min(cnt - base, 64);
        int idxv = (lane < nb) ? ssrc[start + base + lane] : 0;
        int j = 0;
        for (; j + 16 <= nb; j += 16) {
            uint u[16];
#pragma unroll
            for (int q = 0; q < 16; q++) {
                int i = __shfl(idxv, j + q);
                u[q] = hs_b[(size_t)i * 64 + lane];
            }
#pragma unroll
            for (int q = 0; q < 16; q++) {
                a0 += bflo(u[q]);
                a1 += bfhi(u[q]);
            }
        }
        for (; j + 4 <= nb; j += 4) {
            uint u[4];
#pragma unroll
            for (int q = 0; q < 4; q++) {
                int i = __shfl(idxv, j + q);
                u[q] = hs_b[(size_t)i * 64 + lane];
            }
#pragma unroll
            for (int q = 0; q < 4; q++) {
                a0 += bflo(u[q]);
                a1 += bfhi(u[q]);
            }
        }
        for (; j < nb; j++) {
            int i = __shfl(idxv, j);
            uint u = hs_b[(size_t)i * 64 + lane];
            a0 += bflo(u);
            a1 += bfhi(u);
        }
        base += nb;
    }
    float sc = rsqrtf((float)cnt + 1.0f);
    float2 bb = b1[lane];
    rh_b[(size_t)d * 64 + lane] =
        pk(fmaxf(fmaf(a0, sc, bb.x), 0.f), fmaxf(fmaf(a1, sc, bb.y), 0.f));
}

// ---- GEMM2: h2_b = bf16( dinv[i] * (rh @ W2) ), one row per thread ---------

__global__ __launch_bounds__(256) void k_gemm2(const uint* __restrict__ rh_b,
                                               const float* __restrict__ W2,
                                               const int* __restrict__ deg, int N,
                                               uint* __restrict__ h2_b) {
    __shared__ float Wl[D_H * D_OUT];  // 8 KB
    int t = threadIdx.x;
    for (int i = t; i < D_H * D_OUT; i += 256) Wl[i] = W2[i];
    __syncthreads();
    int r = blockIdx.x * 256 + t;
    if (r >= N) return;
    const uint* xrow = rh_b + (size_t)r * 64;
    float acc[16];
#pragma unroll
    for (int f = 0; f < 16; f++) acc[f] = 0.f;
    for (int c = 0; c < 16; c++) {
        uint4 xv = *(const uint4*)(xrow + c * 4);
        uint xs[4] = {xv.x, xv.y, xv.z, xv.w};
#pragma unroll
        for (int u = 0; u < 4; u++) {
            int k = c * 8 + u * 2;
            float x0 = bflo(xs[u]), x1 = bfhi(xs[u]);
            const float* w0 = &Wl[k * 16];
            const float* w1 = &Wl[(k + 1) * 16];
#pragma unroll
            for (int f = 0; f < 16; f++) acc[f] = fmaf(x0, w0[f], acc[f]);
#pragma unroll
            for (int f = 0; f < 16; f++) acc[f] = fmaf(x1, w1[f], acc[f]);
        }
    }
    float sc = rsqrtf((float)deg[r] + 1.0f);
    uint o[8];
#pragma unroll
    for (int q = 0; q < 8; q++) o[q] = pk(acc[2 * q] * sc, acc[2 * q + 1] * sc);
    *(uint4*)&h2_b[(size_t)r * 8] = make_uint4(o[0], o[1], o[2], o[3]);
    *(uint4*)&h2_b[(size_t)r * 8 + 4] = make_uint4(o[4], o[5], o[6], o[7]);
}

// ---- AGG2: wave per node (8 edge slots x 8 uint-features), shfl reduce -----

__global__ __launch_bounds__(256) void k_agg2(const uint* __restrict__ h2_b,
                                              const int* __restrict__ rowptr,
                                              const int* __restrict__ deg,
                                              const int* __restrict__ ssrc,
                                              const float* __restrict__ b2, int N,
                                              float2* __restrict__ out) {
    int w = threadIdx.x >> 6, lane = threadIdx.x & 63;
    int d = blockIdx.x * 4 + w;
    if (d >= N) return;
    int slot = lane >> 3, jp = lane & 7;
    int start = rowptr[d], cnt = deg[d];
    float a0 = 0.f, a1 = 0.f;
    if (slot == 0) {
        uint sv = h2_b[(size_t)d * 8 + jp];  // self-loop
        a0 = bflo(sv);
        a1 = bfhi(sv);
    }
    int base = 0;
    while (base < cnt) {
        int nb = min(cnt - base, 64);
        int idxv = (lane < nb) ? ssrc[start + base + lane] : 0;
        int ng = (nb + 7) >> 3;  // wave-uniform
        if (ng <= 4) {
            int i0 = __shfl(idxv, slot);
            int i1 = __shfl(idxv, 8 + slot);
            int i2 = __shfl(idxv, 16 + slot);
            int i3 = __shfl(idxv, 24 + slot);
            uint u0 = (slot < nb) ? h2_b[(size_t)i0 * 8 + jp] : 0u;
            uint u1 = (8 + slot < nb) ? h2_b[(size_t)i1 * 8 + jp] : 0u;
            uint u2 = (16 + slot < nb) ? h2_b[(size_t)i2 * 8 + jp] : 0u;
            uint u3 = (24 + slot < nb) ? h2_b[(size_t)i3 * 8 + jp] : 0u;
            a0 += bflo(u0) + bflo(u1) + bflo(u2) + bflo(u3);
            a1 += bfhi(u0) + bfhi(u1) + bfhi(u2) + bfhi(u3);
        } else {
            for (int g = 0; g < ng; g++) {
                int j = g * 8 + slot;          // <= 63 always
                int i = __shfl(idxv, j);       // all lanes active here
                if (j < nb) {
                    uint hv = h2_b[(size_t)i * 8 + jp];
                    a0 += bflo(hv);
                    a1 += bfhi(hv);
                }
            }
        }
        base += nb;
    }
    a0 += __shfl_xor(a0, 8);
    a1 += __shfl_xor(a1, 8);
    a0 += __shfl_xor(a0, 16);
    a1 += __shfl_xor(a1, 16);
    a0 += __shfl_xor(a0, 32);
    a1 += __shfl_xor(a1, 32);
    if (slot == 0) {
        float di = rsqrtf((float)cnt + 1.0f);
        out[(size_t)d * 8 + jp] =
            make_float2(fmaf(a0, di, b2[2 * jp]), fmaf(a1, di, b2[2 * jp + 1]));
    }
}

// ---- launch ----------------------------------------------------------------

extern "C" void kernel_launch(void* const* d_in, const int* in_sizes, int n_in,
                              void* d_out, int out_size, void* d_ws, size_t ws_size,
                              hipStream_t stream) {
    const float* x  = (const float*)d_in[0];
    const int*   ei = (const int*)d_in[1];
    const float* W1 = (const float*)d_in[2];
    const float* b1 = (const float*)d_in[3];
    const float* W2 = (const float*)d_in[4];
    const float* b2 = (const float*)d_in[5];
    int N = in_sizes[0] / D_IN;
    int E = in_sizes[1] / 2;
    const int* src = ei;
    const int* dst = ei + E;
    int C = (N + NPC - 1) / NPC;           // 196
    int chunk = (E + P1 - 1) / P1;         // 6250
    int ntiles = (N + 63) / 64;            // 1563

    char* ws = (char*)d_ws;
    size_t off = 0;
    auto alloc = [&](size_t bytes) -> char* {
        char* p = ws + off;
        off = (off + bytes + 255) & ~(size_t)255;
        return p;
    };
    int*   hist1   = (int*)alloc((size_t)P1 * C * 4);
    int*   cbase   = (int*)alloc((size_t)(C + 1) * 4);
    uint*  binned1 = (uint*)alloc((size_t)E * 4);
    int*   ssrc    = (int*)alloc((size_t)E * 4);
    int*   rowptr  = (int*)alloc((size_t)N * 4);
    int*   deg     = (int*)alloc((size_t)N * 4);
    uint*  W1p     = (uint*)alloc((size_t)64 * 128 * 4);    // 32 KB packed W1
    uint*  hs_b    = (uint*)alloc((size_t)N * 64 * 4);      // 25.6 MB bf16-packed
    uint*  rh_b    = (uint*)alloc((size_t)N * 64 * 4);
    uint*  h2_b    = hs_b;  // hs_b dead after k_agg1; reuse

    k_p1hist<<<P1 + 32, 256, 0, stream>>>(dst, E, N, C, chunk, hist1, W1, W1p, deg);
    k_p1scan<<<1, 1024, 0, stream>>>(hist1, C, cbase);
    k_p1fill<<<P1, 256, 0, stream>>>(src, dst, E, N, C, chunk, hist1, binned1, deg);
    int g1 = min(768, ntiles);
    k_p2gemm1<<<C + g1, 256, 0, stream>>>(binned1, cbase, N, C, ssrc, rowptr, deg,
                                          W1p, x, hs_b, ntiles);
    k_agg1<<<(N + 3) / 4, 256, 0, stream>>>(hs_b, rowptr, deg, ssrc,
                                            (const float2*)b1, N, rh_b);
    k_gemm2<<<(N + 255) / 256, 256, 0, stream>>>(rh_b, W2, deg, N, h2_b);
    k_agg2<<<(N + 3) / 4, 256, 0, stream>>>(h2_b, rowptr, deg, ssrc, b2, N,
                                            (float2*)d_out);
}

// Round 9
// 318.199 us; speedup vs baseline: 1.0361x; 1.0361x over previous
//
#include <hip/hip_runtime.h>

typedef unsigned int uint;
typedef __attribute__((ext_vector_type(8))) short bf16x8;
typedef __attribute__((ext_vector_type(4))) float f32x4;

#define D_IN 128
#define D_H  128
#define D_OUT 16
#define NPC 512                // nodes per coarse bucket
#define NPCSH 9
#define CLDS 224               // >= C = ceil(N/NPC) = 196
#define P1 256                 // pass-1 blocks
#define XL_STRIDE 68
#define WT_STRIDE 68

static __device__ __forceinline__ float bflo(uint u) { return __uint_as_float(u << 16); }
static __device__ __forceinline__ float bfhi(uint u) { return __uint_as_float(u & 0xFFFF0000u); }
static __device__ __forceinline__ uint f2bf(float f) {
    uint b = __float_as_uint(f);
    return (b + 0x7FFFu + ((b >> 16) & 1u)) >> 16;  // RNE
}
static __device__ __forceinline__ uint pk(float a, float b) {
    return f2bf(a) | (f2bf(b) << 16);
}

// ---- pass 1: coarse histogram + W1 pre-pack + W2 transpose -----------------
// blocks [0,P1): histogram (hist1 TRANSPOSED: hist1[bucket*P1 + block]).
// blocks [P1,P1+32): pack W1 -> W1p[k2*128+f] = pk(W1[2k2][f], W1[2k2+1][f]).
// block P1+32: W2t[f*128+k] = W2[k*16+f] (8KB, for agg1g2's fused epilogue).

__global__ __launch_bounds__(256) void k_p1hist(const int* __restrict__ dst, int E, int N, int C,
                                                int chunk, int* __restrict__ hist1,
                                                const float* __restrict__ W1,
                                                uint* __restrict__ W1p,
                                                const float* __restrict__ W2,
                                                float* __restrict__ W2t) {
    __shared__ int h[CLDS];
    int t = threadIdx.x, b = blockIdx.x;
    if (b >= P1 + 32) {  // W2 transpose role
        for (int p = t; p < D_H * D_OUT; p += 256) {
            int f = p >> 7, k = p & 127;
            W2t[p] = W2[k * 16 + f];
        }
        return;
    }
    if (b >= P1) {  // W1 pack role
        int p = (b - P1) * 256 + t;  // 32*256 = 8192 = 64*128
        int k2 = p >> 7, f = p & 127;
        float w0 = W1[(size_t)(2 * k2) * 128 + f];
        float w1 = W1[(size_t)(2 * k2 + 1) * 128 + f];
        W1p[p] = pk(w0, w1);
        return;
    }
    for (int i = t; i < C; i += 256) h[i] = 0;
    __syncthreads();
    int e0 = b * chunk, e1 = min(e0 + chunk, E);
    for (int e = e0 + t; e < e1; e += 256) {
        int d = dst[e];
        d = max(0, min(d, N - 1));
        atomicAdd(&h[d >> NPCSH], 1);
    }
    __syncthreads();
    for (int i = t; i < C; i += 256) hist1[(size_t)i * P1 + b] = h[i];
}

// wave-parallel: per-bucket wave scan (int4/lane over 256 counts) -> local
// prefixes; block scan over bucket totals -> cbase; add base back per bucket.
__global__ __launch_bounds__(1024) void k_p1scan(int* __restrict__ hist1, int C,
                                                 int* __restrict__ cbase) {
    __shared__ int col[CLDS];
    __shared__ int sdata[1024];
    int t = threadIdx.x;
    int w = t >> 6, lane = t & 63;
    // Phase A: each wave scans whole buckets (coalesced int4 loads)
    for (int i = w; i < C; i += 16) {
        int4 v = ((const int4*)hist1)[i * 64 + lane];
        int s = v.x + v.y + v.z + v.w;
        int inc = s;
        for (int off = 1; off < 64; off <<= 1) {
            int o = __shfl_up(inc, off);
            if (lane >= off) inc += o;
        }
        int excl = inc - s;
        int4 p;
        p.x = excl;
        p.y = excl + v.x;
        p.z = excl + v.x + v.y;
        p.w = excl + v.x + v.y + v.z;
        ((int4*)hist1)[i * 64 + lane] = p;  // local (bucket-relative) cursors
        if (lane == 63) col[i] = inc;       // bucket total
    }
    __syncthreads();
    // Phase B: block scan over C bucket totals
    int v = (t < C) ? col[t] : 0;
    sdata[t] = v;
    __syncthreads();
    for (int off = 1; off < 1024; off <<= 1) {
        int x = (t >= off) ? sdata[t - off] : 0;
        __syncthreads();
        sdata[t] += x;
        __syncthreads();
    }
    int pos = sdata[t] - v;  // exclusive
    if (t < C) cbase[t] = pos;
    if (t == 1023) cbase[C] = sdata[1023];
    if (t < C) col[t] = pos;  // bucket base for phase C
    __syncthreads();
    // Phase C: same wave owns same buckets -> add bucket base to local cursors
    for (int i = w; i < C; i += 16) {
        int base = col[i];
        int4 p = ((int4*)hist1)[i * 64 + lane];
        p.x += base; p.y += base; p.z += base; p.w += base;
        ((int4*)hist1)[i * 64 + lane] = p;
    }
}

// scatter packed (dst_local_coarse<<17 | src) into coarse regions, LDS cursors only
__global__ __launch_bounds__(256) void k_p1fill(const int* __restrict__ src,
                                                const int* __restrict__ dst, int E, int N, int C,
                                                int chunk, const int* __restrict__ hist1,
                                                uint* __restrict__ binned1) {
    __shared__ int cur[CLDS];
    int t = threadIdx.x, b = blockIdx.x;
    for (int i = t; i < C; i += 256) cur[i] = hist1[(size_t)i * P1 + b];
    __syncthreads();
    int e0 = b * chunk, e1 = min(e0 + chunk, E);
    for (int e = e0 + t; e < e1; e += 256) {
        int d = dst[e];
        d = max(0, min(d, N - 1));
        int s = src[e];
        s = max(0, min(s, N - 1));
        int p = atomicAdd(&cur[d >> NPCSH], 1);
        binned1[p] = ((uint)(d & (NPC - 1)) << 17) | (uint)s;
    }
}

// ---- fused: p2 (fine CSR sort) PARALLEL WITH gemm1 (MFMA, persistent) ------
// blocks [0,C): p2 role -- per-node CSR (rowptr/deg/dinv) + sorted ssrc.
// blocks [C, C+768): gemm1 role -- hs_b = bf16(x @ W1), UNSCALED (dinv applied
// in k_agg1g2), so gemm1 has no dependency on p2 and overlaps it fully.

__global__ __launch_bounds__(256) void k_p2gemm1(const uint* __restrict__ binned1,
                                                 const int* __restrict__ cbase, int N, int C,
                                                 int* __restrict__ ssrc, int* __restrict__ rowptr,
                                                 int* __restrict__ deg, float* __restrict__ dinv,
                                                 const uint* __restrict__ W1p,
                                                 const float* __restrict__ x,
                                                 uint* __restrict__ hs_b, int ntiles) {
    __shared__ uint smem[128 * WT_STRIDE + 64 * XL_STRIDE];  // 52224 B
    int t = threadIdx.x;
    if ((int)blockIdx.x < C) {
        // ---------------- p2 role ----------------
        int* ncnt = (int*)smem;
        int* nbase_ = ncnt + NPC;
        int* sdata = nbase_ + NPC;
        int c = blockIdx.x;
        int start = cbase[c], end = cbase[c + 1];
        for (int i = t; i < NPC; i += 256) ncnt[i] = 0;
        __syncthreads();
        for (int j = start + t; j < end; j += 256) atomicAdd(&ncnt[binned1[j] >> 17], 1);
        __syncthreads();
        // parallel exclusive scan, 2 elements per thread (order-preserving)
        int v0 = ncnt[2 * t], v1 = ncnt[2 * t + 1];
        int s = v0 + v1;
        sdata[t] = s;
        __syncthreads();
        for (int off = 1; off < 256; off <<= 1) {
            int xv = (t >= off) ? sdata[t - off] : 0;
            __syncthreads();
            sdata[t] += xv;
            __syncthreads();
        }
        int pre = sdata[t] - s;
        nbase_[2 * t] = start + pre;
        nbase_[2 * t + 1] = start + pre + v0;
        __syncthreads();
        for (int i = t; i < NPC; i += 256) {
            int node = c * NPC + i;
            if (node < N) {
                deg[node] = ncnt[i];
                rowptr[node] = nbase_[i];
                dinv[node] = rsqrtf((float)ncnt[i] + 1.0f);
            }
        }
        __syncthreads();
        for (int i = t; i < NPC; i += 256) ncnt[i] = nbase_[i];  // reuse as cursors
        __syncthreads();
        for (int j = start + t; j < end; j += 256) {
            uint pe = binned1[j];
            int p = atomicAdd(&ncnt[pe >> 17], 1);
            ssrc[p] = (int)(pe & 0x1FFFFu);
        }
        return;
    }
    // ---------------- gemm1 role ----------------
    uint* Wt = smem;                        // [f][k2] bf16 pairs
    uint* xl = smem + 128 * WT_STRIDE;      // [row][k2] bf16 pairs; reused as out
    int role = blockIdx.x - C;
    int nroles = gridDim.x - C;
    for (int p = t; p < 64 * 128; p += 256) {
        int k2 = p >> 7, f = p & 127;
        Wt[f * WT_STRIDE + k2] = W1p[p];
    }
    int w = t >> 6, lane = t & 63;
    int q = lane >> 4, m = lane & 15;
    const float4* x4 = (const float4*)x;
    for (int tile = role; tile < ntiles; tile += nroles) {
        int row0 = tile * 64;
        __syncthreads();  // Wt ready (iter 0) / outl fully drained (iters > 0)
        for (int p = t; p < 64 * 32; p += 256) {
            int r = p >> 5, c2 = p & 31;
            int gr = row0 + r;
            float4 v = (gr < N) ? x4[(size_t)gr * 32 + c2] : make_float4(0.f, 0.f, 0.f, 0.f);
            *(uint2*)&xl[r * XL_STRIDE + 2 * c2] = make_uint2(pk(v.x, v.y), pk(v.z, v.w));
        }
        __syncthreads();
        // preload all A fragments (xl dead afterwards)
        bf16x8 afr[4][4];
#pragma unroll
        for (int rt = 0; rt < 4; rt++)
#pragma unroll
            for (int kc = 0; kc < 4; kc++)
                afr[rt][kc] = *(const bf16x8*)&xl[(rt * 16 + m) * XL_STRIDE + kc * 16 + q * 4];
        f32x4 acc[2][4];
#pragma unroll
        for (int c = 0; c < 2; c++)
#pragma unroll
            for (int rt = 0; rt < 4; rt++) acc[c][rt] = (f32x4){0.f, 0.f, 0.f, 0.f};
#pragma unroll
        for (int c = 0; c < 2; c++) {
            int f = w * 32 + c * 16 + m;
#pragma unroll
            for (int kc = 0; kc < 4; kc++) {
                bf16x8 bfr = *(const bf16x8*)&Wt[f * WT_STRIDE + kc * 16 + q * 4];
#pragma unroll
                for (int rt = 0; rt < 4; rt++)
                    acc[c][rt] = __builtin_amdgcn_mfma_f32_16x16x32_bf16(afr[rt][kc], bfr,
                                                                         acc[c][rt], 0, 0, 0);
            }
        }
        __syncthreads();  // all waves done reading xl
        uint* outl = xl;  // 64 x 65 packed out tile
#pragma unroll
        for (int rt = 0; rt < 4; rt++) {
#pragma unroll
            for (int c = 0; c < 2; c++) {
                f32x4 a = acc[c][rt];
#pragma unroll
                for (int r = 0; r < 4; r++) {
                    float v = a[r];  // UNSCALED: dinv applied in k_agg1g2
                    float vn = __shfl_xor(v, 1);
                    if (!(lane & 1)) {
                        int row = rt * 16 + q * 4 + r;
                        int cp = (w * 32 + c * 16 + m) >> 1;
                        outl[row * 65 + cp] = pk(v, vn);
                    }
                }
            }
        }
        __syncthreads();
        for (int p = t; p < 64 * 64; p += 256) {
            int r = p >> 6, cc = p & 63;
            int gr = row0 + r;
            if (gr < N) hs_b[(size_t)gr * 64 + cc] = outl[r * 65 + cc];
        }
    }
}

// ---- AGG1 + GEMM2 fused: wave per node -------------------------------------
// Gather-sum UNSCALED hs_b rows with per-neighbor dinv (R5's proven 73.8us
// loop), compute rh in-register, then the 128x16 W2 product via a per-wave
// LDS strip (NO barriers, NO butterfly -- R6's 96-shfl mistake): wave writes
// its f32 rh row to LDS (1 ds_write_b64/lane), lane (kc,f) dots rh[kc*32..+31]
// (8 ds_read_b128, broadcast within 16-lane groups = conflict-free) against
// W2t (L1-resident), 2 shfl_xor reduce + 1 pack shfl. h2 written directly.

__global__ __launch_bounds__(256) void k_agg1g2(const uint* __restrict__ hs_b,
                                                const int* __restrict__ rowptr,
                                                const int* __restrict__ deg,
                                                const int* __restrict__ ssrc,
                                                const float* __restrict__ dinv,
                                                const float2* __restrict__ b1,
                                                const float* __restrict__ W2t, int N,
                                                uint* __restrict__ h2_b) {
    __shared__ float rhs[4][128];  // per-wave rh strip, 2KB
    int w = threadIdx.x >> 6, lane = threadIdx.x & 63;
    int d = blockIdx.x * 4 + w;
    if (d >= N) return;
    int start = rowptr[d], cnt = deg[d];
    float sc = dinv[d];
    uint sv = hs_b[(size_t)d * 64 + lane];  // self-loop (unscaled)
    float a0 = bflo(sv) * sc, a1 = bfhi(sv) * sc;
    int base = 0;
    while (base < cnt) {
        int nb = min(cnt - base, 64);
        int idxv = (lane < nb) ? ssrc[start + base + lane] : 0;
        float dvv = dinv[idxv];  // idxv=0 for inactive lanes: valid, unused
        int j = 0;
        for (; j + 16 <= nb; j += 16) {
            uint u[16];
            float dv[16];
#pragma unroll
            for (int q = 0; q < 16; q++) {
                int i = __shfl(idxv, j + q);
                dv[q] = __shfl(dvv, j + q);
                u[q] = hs_b[(size_t)i * 64 + lane];
            }
#pragma unroll
            for (int q = 0; q < 16; q++) {
                a0 = fmaf(bflo(u[q]), dv[q], a0);
                a1 = fmaf(bfhi(u[q]), dv[q], a1);
            }
        }
        for (; j + 4 <= nb; j += 4) {
            uint u[4];
            float dv[4];
#pragma unroll
            for (int q = 0; q < 4; q++) {
                int i = __shfl(idxv, j + q);
                dv[q] = __shfl(dvv, j + q);
                u[q] = hs_b[(size_t)i * 64 + lane];
            }
#pragma unroll
            for (int q = 0; q < 4; q++) {
                a0 = fmaf(bflo(u[q]), dv[q], a0);
                a1 = fmaf(bfhi(u[q]), dv[q], a1);
            }
        }
        for (; j < nb; j++) {
            int i = __shfl(idxv, j);
            float dv = __shfl(dvv, j);
            uint u = hs_b[(size_t)i * 64 + lane];
            a0 = fmaf(bflo(u), dv, a0);
            a1 = fmaf(bfhi(u), dv, a1);
        }
        base += nb;
    }
    float2 bb = b1[lane];
    float r0 = fmaxf(fmaf(a0, sc, bb.x), 0.f);  // rh features 2*lane, 2*lane+1 (f32)
    float r1 = fmaxf(fmaf(a1, sc, bb.y), 0.f);
    // share rh across the wave via LDS (same-wave DS ops are ordered; no barrier)
    ((float2*)rhs[w])[lane] = make_float2(r0, r1);
    int f = lane & 15, kc = lane >> 4;
    const float4* rp = (const float4*)&rhs[w][kc * 32];
    const float4* wt = (const float4*)(W2t + (size_t)f * 128 + kc * 32);
    float pacc = 0.f;
#pragma unroll
    for (int j8 = 0; j8 < 8; j8++) {
        float4 rv = rp[j8];
        float4 wv = wt[j8];
        pacc = fmaf(rv.x, wv.x, pacc);
        pacc = fmaf(rv.y, wv.y, pacc);
        pacc = fmaf(rv.z, wv.z, pacc);
        pacc = fmaf(rv.w, wv.w, pacc);
    }
    pacc += __shfl_xor(pacc, 16);
    pacc += __shfl_xor(pacc, 32);       // lanes 0..15 hold p[f] (replicated)
    float pn = __shfl_xor(pacc, 1);     // p[f^1]
    if (lane < 16 && !(lane & 1))
        h2_b[(size_t)d * 8 + (lane >> 1)] = pk(pacc * sc, pn * sc);
}

// ---- AGG2: wave per node (8 edge slots x 8 uint-features), shfl reduce -----

__global__ __launch_bounds__(256) void k_agg2(const uint* __restrict__ h2_b,
                                              const int* __restrict__ rowptr,
                                              const int* __restrict__ deg,
                                              const int* __restrict__ ssrc,
                                              const float* __restrict__ dinv,
                                              const float* __restrict__ b2, int N,
                                              float2* __restrict__ out) {
    int w = threadIdx.x >> 6, lane = threadIdx.x & 63;
    int d = blockIdx.x * 4 + w;
    if (d >= N) return;
    int slot = lane >> 3, jp = lane & 7;
    int start = rowptr[d], cnt = deg[d];
    float a0 = 0.f, a1 = 0.f;
    if (slot == 0) {
        uint sv = h2_b[(size_t)d * 8 + jp];  // self-loop
        a0 = bflo(sv);
        a1 = bfhi(sv);
    }
    int base = 0;
    while (base < cnt) {
        int nb = min(cnt - base, 64);
        int idxv = (lane < nb) ? ssrc[start + base + lane] : 0;
        int ng = (nb + 7) >> 3;  // wave-uniform
        if (ng <= 4) {
            int i0 = __shfl(idxv, slot);
            int i1 = __shfl(idxv, 8 + slot);
            int i2 = __shfl(idxv, 16 + slot);
            int i3 = __shfl(idxv, 24 + slot);
            uint u0 = (slot < nb) ? h2_b[(size_t)i0 * 8 + jp] : 0u;
            uint u1 = (8 + slot < nb) ? h2_b[(size_t)i1 * 8 + jp] : 0u;
            uint u2 = (16 + slot < nb) ? h2_b[(size_t)i2 * 8 + jp] : 0u;
            uint u3 = (24 + slot < nb) ? h2_b[(size_t)i3 * 8 + jp] : 0u;
            a0 += bflo(u0) + bflo(u1) + bflo(u2) + bflo(u3);
            a1 += bfhi(u0) + bfhi(u1) + bfhi(u2) + bfhi(u3);
        } else {
            for (int g = 0; g < ng; g++) {
                int j = g * 8 + slot;          // <= 63 always
                int i = __shfl(idxv, j);       // all lanes active here
                if (j < nb) {
                    uint hv = h2_b[(size_t)i * 8 + jp];
                    a0 += bflo(hv);
                    a1 += bfhi(hv);
                }
            }
        }
        base += nb;
    }
    a0 += __shfl_xor(a0, 8);
    a1 += __shfl_xor(a1, 8);
    a0 += __shfl_xor(a0, 16);
    a1 += __shfl_xor(a1, 16);
    a0 += __shfl_xor(a0, 32);
    a1 += __shfl_xor(a1, 32);
    if (slot == 0) {
        float di = dinv[d];
        out[(size_t)d * 8 + jp] =
            make_float2(fmaf(a0, di, b2[2 * jp]), fmaf(a1, di, b2[2 * jp + 1]));
    }
}

// ---- launch ----------------------------------------------------------------

extern "C" void kernel_launch(void* const* d_in, const int* in_sizes, int n_in,
                              void* d_out, int out_size, void* d_ws, size_t ws_size,
                              hipStream_t stream) {
    const float* x  = (const float*)d_in[0];
    const int*   ei = (const int*)d_in[1];
    const float* W1 = (const float*)d_in[2];
    const float* b1 = (const float*)d_in[3];
    const float* W2 = (const float*)d_in[4];
    const float* b2 = (const float*)d_in[5];
    int N = in_sizes[0] / D_IN;
    int E = in_sizes[1] / 2;
    const int* src = ei;
    const int* dst = ei + E;
    int C = (N + NPC - 1) / NPC;           // 196
    int chunk = (E + P1 - 1) / P1;         // 6250
    int ntiles = (N + 63) / 64;            // 1563

    char* ws = (char*)d_ws;
    size_t off = 0;
    auto alloc = [&](size_t bytes) -> char* {
        char* p = ws + off;
        off = (off + bytes + 255) & ~(size_t)255;
        return p;
    };
    int*   hist1   = (int*)alloc((size_t)P1 * C * 4);
    int*   cbase   = (int*)alloc((size_t)(C + 1) * 4);
    uint*  binned1 = (uint*)alloc((size_t)E * 4);
    int*   ssrc    = (int*)alloc((size_t)E * 4);
    int*   rowptr  = (int*)alloc((size_t)N * 4);
    int*   deg     = (int*)alloc((size_t)N * 4);
    float* dinv    = (float*)alloc((size_t)N * 4);
    uint*  W1p     = (uint*)alloc((size_t)64 * 128 * 4);    // 32 KB packed W1
    float* W2t     = (float*)alloc((size_t)D_H * D_OUT * 4);  // 8 KB W2 transposed
    uint*  hs_b    = (uint*)alloc((size_t)N * 64 * 4);      // 25.6 MB bf16-packed
    uint*  h2_b    = (uint*)alloc((size_t)N * 8 * 4);       // 3.2 MB (rh never stored)

    k_p1hist<<<P1 + 33, 256, 0, stream>>>(dst, E, N, C, chunk, hist1, W1, W1p, W2, W2t);
    k_p1scan<<<1, 1024, 0, stream>>>(hist1, C, cbase);
    k_p1fill<<<P1, 256, 0, stream>>>(src, dst, E, N, C, chunk, hist1, binned1);
    int g1 = min(768, ntiles);
    k_p2gemm1<<<C + g1, 256, 0, stream>>>(binned1, cbase, N, C, ssrc, rowptr, deg, dinv,
                                          W1p, x, hs_b, ntiles);
    k_agg1g2<<<(N + 3) / 4, 256, 0, stream>>>(hs_b, rowptr, deg, ssrc, dinv,
                                              (const float2*)b1, W2t, N, h2_b);
    k_agg2<<<(N + 3) / 4, 256, 0, stream>>>(h2_b, rowptr, deg, ssrc, dinv, b2, N,
                                            (float2*)d_out);
}

// Round 10
// 270.157 us; speedup vs baseline: 1.2203x; 1.1778x over previous
//
#include <hip/hip_runtime.h>

typedef unsigned int uint;
typedef __attribute__((ext_vector_type(8))) short bf16x8;
typedef __attribute__((ext_vector_type(4))) float f32x4;

#define D_IN 128
#define D_H  128
#define D_OUT 16
#define NPC 512                // nodes per coarse bucket
#define NPCSH 9
#define CLDS 224               // >= C = ceil(N/NPC) = 196
#define P1 256                 // pass-1 blocks
#define XL_STRIDE 68
#define WT_STRIDE 68

static __device__ __forceinline__ float bflo(uint u) { return __uint_as_float(u << 16); }
static __device__ __forceinline__ float bfhi(uint u) { return __uint_as_float(u & 0xFFFF0000u); }
static __device__ __forceinline__ uint f2bf(float f) {
    uint b = __float_as_uint(f);
    return (b + 0x7FFFu + ((b >> 16) & 1u)) >> 16;  // RNE
}
static __device__ __forceinline__ uint pk(float a, float b) {
    return f2bf(a) | (f2bf(b) << 16);
}

// ---- pass 1: coarse histogram + (fused) W1 pre-pack ------------------------
// blocks [0,P1): histogram (hist1 TRANSPOSED: hist1[bucket*P1 + block]).
// blocks [P1,P1+32): pack W1 -> W1p[k2*128+f] = pk(W1[2k2][f], W1[2k2+1][f]).

__global__ __launch_bounds__(256) void k_p1hist(const int* __restrict__ dst, int E, int N, int C,
                                                int chunk, int* __restrict__ hist1,
                                                const float* __restrict__ W1,
                                                uint* __restrict__ W1p) {
    __shared__ int h[CLDS];
    int t = threadIdx.x, b = blockIdx.x;
    if (b >= P1) {  // W1 pack role
        int p = (b - P1) * 256 + t;  // 32*256 = 8192 = 64*128
        int k2 = p >> 7, f = p & 127;
        float w0 = W1[(size_t)(2 * k2) * 128 + f];
        float w1 = W1[(size_t)(2 * k2 + 1) * 128 + f];
        W1p[p] = pk(w0, w1);
        return;
    }
    for (int i = t; i < C; i += 256) h[i] = 0;
    __syncthreads();
    int e0 = b * chunk, e1 = min(e0 + chunk, E);
    for (int e = e0 + t; e < e1; e += 256) {
        int d = dst[e];
        d = max(0, min(d, N - 1));
        atomicAdd(&h[d >> NPCSH], 1);
    }
    __syncthreads();
    for (int i = t; i < C; i += 256) hist1[(size_t)i * P1 + b] = h[i];
}

// wave-parallel: per-bucket wave scan (int4/lane over 256 counts) -> local
// prefixes; block scan over bucket totals -> cbase; add base back per bucket.
__global__ __launch_bounds__(1024) void k_p1scan(int* __restrict__ hist1, int C,
                                                 int* __restrict__ cbase) {
    __shared__ int col[CLDS];
    __shared__ int sdata[1024];
    int t = threadIdx.x;
    int w = t >> 6, lane = t & 63;
    // Phase A: each wave scans whole buckets (coalesced int4 loads)
    for (int i = w; i < C; i += 16) {
        int4 v = ((const int4*)hist1)[i * 64 + lane];
        int s = v.x + v.y + v.z + v.w;
        int inc = s;
        for (int off = 1; off < 64; off <<= 1) {
            int o = __shfl_up(inc, off);
            if (lane >= off) inc += o;
        }
        int excl = inc - s;
        int4 p;
        p.x = excl;
        p.y = excl + v.x;
        p.z = excl + v.x + v.y;
        p.w = excl + v.x + v.y + v.z;
        ((int4*)hist1)[i * 64 + lane] = p;  // local (bucket-relative) cursors
        if (lane == 63) col[i] = inc;       // bucket total
    }
    __syncthreads();
    // Phase B: block scan over C bucket totals
    int v = (t < C) ? col[t] : 0;
    sdata[t] = v;
    __syncthreads();
    for (int off = 1; off < 1024; off <<= 1) {
        int x = (t >= off) ? sdata[t - off] : 0;
        __syncthreads();
        sdata[t] += x;
        __syncthreads();
    }
    int pos = sdata[t] - v;  // exclusive
    if (t < C) cbase[t] = pos;
    if (t == 1023) cbase[C] = sdata[1023];
    if (t < C) col[t] = pos;  // bucket base for phase C
    __syncthreads();
    // Phase C: same wave owns same buckets -> add bucket base to local cursors
    for (int i = w; i < C; i += 16) {
        int base = col[i];
        int4 p = ((int4*)hist1)[i * 64 + lane];
        p.x += base; p.y += base; p.z += base; p.w += base;
        ((int4*)hist1)[i * 64 + lane] = p;
    }
}

// scatter packed (dst_local_coarse<<17 | src) into coarse regions, LDS cursors only
__global__ __launch_bounds__(256) void k_p1fill(const int* __restrict__ src,
                                                const int* __restrict__ dst, int E, int N, int C,
                                                int chunk, const int* __restrict__ hist1,
                                                uint* __restrict__ binned1) {
    __shared__ int cur[CLDS];
    int t = threadIdx.x, b = blockIdx.x;
    for (int i = t; i < C; i += 256) cur[i] = hist1[(size_t)i * P1 + b];
    __syncthreads();
    int e0 = b * chunk, e1 = min(e0 + chunk, E);
    for (int e = e0 + t; e < e1; e += 256) {
        int d = dst[e];
        d = max(0, min(d, N - 1));
        int s = src[e];
        s = max(0, min(s, N - 1));
        int p = atomicAdd(&cur[d >> NPCSH], 1);
        binned1[p] = ((uint)(d & (NPC - 1)) << 17) | (uint)s;
    }
}

// ---- fused: p2 (fine CSR sort) PARALLEL WITH gemm1 (MFMA, persistent) ------
// blocks [0,C): p2 role -- per-node CSR (rowptr/deg/dinv) + sorted ssrc.
// blocks [C, C+768): gemm1 role -- hs = bf16(x @ W1), UNSCALED (dinv applied
// per-neighbor in k_agg1), stored HALF-SPLIT: hs_b[half*N*32 + node*32 + c]
// so agg1 can pin each 128B half to a 4-XCD group (L2 replication 7x -> 4x).

__global__ __launch_bounds__(256) void k_p2gemm1(const uint* __restrict__ binned1,
                                                 const int* __restrict__ cbase, int N, int C,
                                                 int* __restrict__ ssrc, int* __restrict__ rowptr,
                                                 int* __restrict__ deg, float* __restrict__ dinv,
                                                 const uint* __restrict__ W1p,
                                                 const float* __restrict__ x,
                                                 uint* __restrict__ hs_b, int ntiles) {
    __shared__ uint smem[128 * WT_STRIDE + 64 * XL_STRIDE];  // 52224 B
    int t = threadIdx.x;
    if ((int)blockIdx.x < C) {
        // ---------------- p2 role ----------------
        int* ncnt = (int*)smem;
        int* nbase_ = ncnt + NPC;
        int* sdata = nbase_ + NPC;
        int c = blockIdx.x;
        int start = cbase[c], end = cbase[c + 1];
        for (int i = t; i < NPC; i += 256) ncnt[i] = 0;
        __syncthreads();
        for (int j = start + t; j < end; j += 256) atomicAdd(&ncnt[binned1[j] >> 17], 1);
        __syncthreads();
        // parallel exclusive scan, 2 elements per thread (order-preserving)
        int v0 = ncnt[2 * t], v1 = ncnt[2 * t + 1];
        int s = v0 + v1;
        sdata[t] = s;
        __syncthreads();
        for (int off = 1; off < 256; off <<= 1) {
            int xv = (t >= off) ? sdata[t - off] : 0;
            __syncthreads();
            sdata[t] += xv;
            __syncthreads();
        }
        int pre = sdata[t] - s;
        nbase_[2 * t] = start + pre;
        nbase_[2 * t + 1] = start + pre + v0;
        __syncthreads();
        for (int i = t; i < NPC; i += 256) {
            int node = c * NPC + i;
            if (node < N) {
                deg[node] = ncnt[i];
                rowptr[node] = nbase_[i];
                dinv[node] = rsqrtf((float)ncnt[i] + 1.0f);
            }
        }
        __syncthreads();
        for (int i = t; i < NPC; i += 256) ncnt[i] = nbase_[i];  // reuse as cursors
        __syncthreads();
        for (int j = start + t; j < end; j += 256) {
            uint pe = binned1[j];
            int p = atomicAdd(&ncnt[pe >> 17], 1);
            ssrc[p] = (int)(pe & 0x1FFFFu);
        }
        return;
    }
    // ---------------- gemm1 role ----------------
    uint* Wt = smem;                        // [f][k2] bf16 pairs
    uint* xl = smem + 128 * WT_STRIDE;      // [row][k2] bf16 pairs; reused as out
    int role = blockIdx.x - C;
    int nroles = gridDim.x - C;
    for (int p = t; p < 64 * 128; p += 256) {
        int k2 = p >> 7, f = p & 127;
        Wt[f * WT_STRIDE + k2] = W1p[p];
    }
    int w = t >> 6, lane = t & 63;
    int q = lane >> 4, m = lane & 15;
    const float4* x4 = (const float4*)x;
    for (int tile = role; tile < ntiles; tile += nroles) {
        int row0 = tile * 64;
        __syncthreads();  // Wt ready (iter 0) / outl fully drained (iters > 0)
        for (int p = t; p < 64 * 32; p += 256) {
            int r = p >> 5, c2 = p & 31;
            int gr = row0 + r;
            float4 v = (gr < N) ? x4[(size_t)gr * 32 + c2] : make_float4(0.f, 0.f, 0.f, 0.f);
            *(uint2*)&xl[r * XL_STRIDE + 2 * c2] = make_uint2(pk(v.x, v.y), pk(v.z, v.w));
        }
        __syncthreads();
        // preload all A fragments (xl dead afterwards)
        bf16x8 afr[4][4];
#pragma unroll
        for (int rt = 0; rt < 4; rt++)
#pragma unroll
            for (int kc = 0; kc < 4; kc++)
                afr[rt][kc] = *(const bf16x8*)&xl[(rt * 16 + m) * XL_STRIDE + kc * 16 + q * 4];
        f32x4 acc[2][4];
#pragma unroll
        for (int c = 0; c < 2; c++)
#pragma unroll
            for (int rt = 0; rt < 4; rt++) acc[c][rt] = (f32x4){0.f, 0.f, 0.f, 0.f};
#pragma unroll
        for (int c = 0; c < 2; c++) {
            int f = w * 32 + c * 16 + m;
#pragma unroll
            for (int kc = 0; kc < 4; kc++) {
                bf16x8 bfr = *(const bf16x8*)&Wt[f * WT_STRIDE + kc * 16 + q * 4];
#pragma unroll
                for (int rt = 0; rt < 4; rt++)
                    acc[c][rt] = __builtin_amdgcn_mfma_f32_16x16x32_bf16(afr[rt][kc], bfr,
                                                                         acc[c][rt], 0, 0, 0);
            }
        }
        __syncthreads();  // all waves done reading xl
        uint* outl = xl;  // 64 x 65 packed out tile
#pragma unroll
        for (int rt = 0; rt < 4; rt++) {
#pragma unroll
            for (int c = 0; c < 2; c++) {
                f32x4 a = acc[c][rt];
#pragma unroll
                for (int r = 0; r < 4; r++) {
                    float v = a[r];  // UNSCALED: dinv applied in k_agg1
                    float vn = __shfl_xor(v, 1);
                    if (!(lane & 1)) {
                        int row = rt * 16 + q * 4 + r;
                        int cp = (w * 32 + c * 16 + m) >> 1;
                        outl[row * 65 + cp] = pk(v, vn);
                    }
                }
            }
        }
        __syncthreads();
        for (int p = t; p < 64 * 64; p += 256) {
            int r = p >> 6, cc = p & 63;
            int gr = row0 + r;
            if (gr < N)
                hs_b[(size_t)(cc >> 5) * N * 32 + (size_t)gr * 32 + (cc & 31)] =
                    outl[r * 65 + cc];
        }
    }
}

// ---- AGG1: XCD-half-split gather -------------------------------------------
// hs_b is [2][N][32] (128B half-rows). Block B: xcd=B&7 (round-robin blockIdx
// ->XCD), half=xcd>>2 -- so half 0 is only ever gathered by XCDs 0-3, half 1
// by XCDs 4-7: per-XCD L2 replication drops ~7x -> ~4x (FETCH 192->~105MB).
// Wave = 2 nodes x 32 lanes; loop bounds wave-uniform via cmax; per-half adds
// masked by zeroing the dinv factor. All shfls run with 64 active lanes.

__global__ __launch_bounds__(256) void k_agg1(const uint* __restrict__ hs_b,
                                              const int* __restrict__ rowptr,
                                              const int* __restrict__ deg,
                                              const int* __restrict__ ssrc,
                                              const float* __restrict__ dinv,
                                              const float2* __restrict__ b1, int N,
                                              uint* __restrict__ rh_b) {
    int t = threadIdx.x;
    int w = t >> 6, lane = t & 63;
    int B = blockIdx.x;
    int xcd = B & 7;
    int half = xcd >> 2;
    int slot = xcd & 3;
    int g = B >> 3;
    int d = g * 32 + slot * 8 + w * 2 + (lane >> 5);  // this half-wave's node
    bool act = (d < N);
    int dd = act ? d : 0;
    int start = rowptr[dd];
    int cnt = act ? deg[dd] : 0;
    int fl = lane & 31;
    const uint* hsH = hs_b + (size_t)half * N * 32;
    float scd = dinv[dd];
    uint sv = hsH[(size_t)dd * 32 + fl];  // self-loop (unscaled)
    float a0 = bflo(sv) * scd, a1 = bfhi(sv) * scd;
    int cnt_o = __shfl(cnt, lane ^ 32);
    int cmax = max(cnt, cnt_o);  // wave-uniform
    int base = 0;
    while (base < cmax) {
        int nb = min(cmax - base, 32);                    // wave-uniform
        int nbh = min(max(cnt - base, 0), 32);            // per-half valid count
        int idxv = (fl < nbh) ? ssrc[start + base + fl] : 0;
        float dvv = dinv[idxv];
        int j = 0;
        for (; j + 16 <= nb; j += 16) {
            uint u[16];
            float dv[16];
#pragma unroll
            for (int q = 0; q < 16; q++) {
                int sj = (lane & 32) | (j + q);
                int i = __shfl(idxv, sj);
                float dq = __shfl(dvv, sj);
                dv[q] = (j + q < nbh) ? dq : 0.f;
                u[q] = hsH[(size_t)i * 32 + fl];
            }
#pragma unroll
            for (int q = 0; q < 16; q++) {
                a0 = fmaf(bflo(u[q]), dv[q], a0);
                a1 = fmaf(bfhi(u[q]), dv[q], a1);
            }
        }
        for (; j + 4 <= nb; j += 4) {
            uint u[4];
            float dv[4];
#pragma unroll
            for (int q = 0; q < 4; q++) {
                int sj = (lane & 32) | (j + q);
                int i = __shfl(idxv, sj);
                float dq = __shfl(dvv, sj);
                dv[q] = (j + q < nbh) ? dq : 0.f;
                u[q] = hsH[(size_t)i * 32 + fl];
            }
#pragma unroll
            for (int q = 0; q < 4; q++) {
                a0 = fmaf(bflo(u[q]), dv[q], a0);
                a1 = fmaf(bfhi(u[q]), dv[q], a1);
            }
        }
        for (; j < nb; j++) {
            int sj = (lane & 32) | j;
            int i = __shfl(idxv, sj);
            float dq = __shfl(dvv, sj);
            float dv = (j < nbh) ? dq : 0.f;
            uint u = hsH[(size_t)i * 32 + fl];
            a0 = fmaf(bflo(u), dv, a0);
            a1 = fmaf(bfhi(u), dv, a1);
        }
        base += nb;
    }
    if (act) {
        float2 bb = b1[half * 32 + fl];
        rh_b[(size_t)dd * 64 + half * 32 + fl] =
            pk(fmaxf(fmaf(a0, scd, bb.x), 0.f), fmaxf(fmaf(a1, scd, bb.y), 0.f));
    }
}

// ---- GEMM2: h2_b = bf16( dinv[i] * (rh @ W2) ), one row per thread ---------

__global__ __launch_bounds__(256) void k_gemm2(const uint* __restrict__ rh_b,
                                               const float* __restrict__ W2,
                                               const float* __restrict__ dinv, int N,
                                               uint* __restrict__ h2_b) {
    __shared__ float Wl[D_H * D_OUT];  // 8 KB
    int t = threadIdx.x;
    for (int i = t; i < D_H * D_OUT; i += 256) Wl[i] = W2[i];
    __syncthreads();
    int r = blockIdx.x * 256 + t;
    if (r >= N) return;
    const uint* xrow = rh_b + (size_t)r * 64;
    float acc[16];
#pragma unroll
    for (int f = 0; f < 16; f++) acc[f] = 0.f;
    for (int c = 0; c < 16; c++) {
        uint4 xv = *(const uint4*)(xrow + c * 4);
        uint xs[4] = {xv.x, xv.y, xv.z, xv.w};
#pragma unroll
        for (int u = 0; u < 4; u++) {
            int k = c * 8 + u * 2;
            float x0 = bflo(xs[u]), x1 = bfhi(xs[u]);
            const float* w0 = &Wl[k * 16];
            const float* w1 = &Wl[(k + 1) * 16];
#pragma unroll
            for (int f = 0; f < 16; f++) acc[f] = fmaf(x0, w0[f], acc[f]);
#pragma unroll
            for (int f = 0; f < 16; f++) acc[f] = fmaf(x1, w1[f], acc[f]);
        }
    }
    float sc = dinv[r];
    uint o[8];
#pragma unroll
    for (int q = 0; q < 8; q++) o[q] = pk(acc[2 * q] * sc, acc[2 * q + 1] * sc);
    *(uint4*)&h2_b[(size_t)r * 8] = make_uint4(o[0], o[1], o[2], o[3]);
    *(uint4*)&h2_b[(size_t)r * 8 + 4] = make_uint4(o[4], o[5], o[6], o[7]);
}

// ---- AGG2: wave per node (8 edge slots x 8 uint-features), shfl reduce -----

__global__ __launch_bounds__(256) void k_agg2(const uint* __restrict__ h2_b,
                                              const int* __restrict__ rowptr,
                                              const int* __restrict__ deg,
                                              const int* __restrict__ ssrc,
                                              const float* __restrict__ dinv,
                                              const float* __restrict__ b2, int N,
                                              float2* __restrict__ out) {
    int w = threadIdx.x >> 6, lane = threadIdx.x & 63;
    int d = blockIdx.x * 4 + w;
    if (d >= N) return;
    int slot = lane >> 3, jp = lane & 7;
    int start = rowptr[d], cnt = deg[d];
    float a0 = 0.f, a1 = 0.f;
    if (slot == 0) {
        uint sv = h2_b[(size_t)d * 8 + jp];  // self-loop
        a0 = bflo(sv);
        a1 = bfhi(sv);
    }
    int base = 0;
    while (base < cnt) {
        int nb = min(cnt - base, 64);
        int idxv = (lane < nb) ? ssrc[start + base + lane] : 0;
        int ng = (nb + 7) >> 3;  // wave-uniform
        if (ng <= 4) {
            int i0 = __shfl(idxv, slot);
            int i1 = __shfl(idxv, 8 + slot);
            int i2 = __shfl(idxv, 16 + slot);
            int i3 = __shfl(idxv, 24 + slot);
            uint u0 = (slot < nb) ? h2_b[(size_t)i0 * 8 + jp] : 0u;
            uint u1 = (8 + slot < nb) ? h2_b[(size_t)i1 * 8 + jp] : 0u;
            uint u2 = (16 + slot < nb) ? h2_b[(size_t)i2 * 8 + jp] : 0u;
            uint u3 = (24 + slot < nb) ? h2_b[(size_t)i3 * 8 + jp] : 0u;
            a0 += bflo(u0) + bflo(u1) + bflo(u2) + bflo(u3);
            a1 += bfhi(u0) + bfhi(u1) + bfhi(u2) + bfhi(u3);
        } else {
            for (int g = 0; g < ng; g++) {
                int j = g * 8 + slot;          // <= 63 always
                int i = __shfl(idxv, j);       // all lanes active here
                if (j < nb) {
                    uint hv = h2_b[(size_t)i * 8 + jp];
                    a0 += bflo(hv);
                    a1 += bfhi(hv);
                }
            }
        }
        base += nb;
    }
    a0 += __shfl_xor(a0, 8);
    a1 += __shfl_xor(a1, 8);
    a0 += __shfl_xor(a0, 16);
    a1 += __shfl_xor(a1, 16);
    a0 += __shfl_xor(a0, 32);
    a1 += __shfl_xor(a1, 32);
    if (slot == 0) {
        float di = dinv[d];
        out[(size_t)d * 8 + jp] =
            make_float2(fmaf(a0, di, b2[2 * jp]), fmaf(a1, di, b2[2 * jp + 1]));
    }
}

// ---- launch ----------------------------------------------------------------

extern "C" void kernel_launch(void* const* d_in, const int* in_sizes, int n_in,
                              void* d_out, int out_size, void* d_ws, size_t ws_size,
                              hipStream_t stream) {
    const float* x  = (const float*)d_in[0];
    const int*   ei = (const int*)d_in[1];
    const float* W1 = (const float*)d_in[2];
    const float* b1 = (const float*)d_in[3];
    const float* W2 = (const float*)d_in[4];
    const float* b2 = (const float*)d_in[5];
    int N = in_sizes[0] / D_IN;
    int E = in_sizes[1] / 2;
    const int* src = ei;
    const int* dst = ei + E;
    int C = (N + NPC - 1) / NPC;           // 196
    int chunk = (E + P1 - 1) / P1;         // 6250
    int ntiles = (N + 63) / 64;            // 1563

    char* ws = (char*)d_ws;
    size_t off = 0;
    auto alloc = [&](size_t bytes) -> char* {
        char* p = ws + off;
        off = (off + bytes + 255) & ~(size_t)255;
        return p;
    };
    int*   hist1   = (int*)alloc((size_t)P1 * C * 4);
    int*   cbase   = (int*)alloc((size_t)(C + 1) * 4);
    uint*  binned1 = (uint*)alloc((size_t)E * 4);
    int*   ssrc    = (int*)alloc((size_t)E * 4);
    int*   rowptr  = (int*)alloc((size_t)N * 4);
    int*   deg     = (int*)alloc((size_t)N * 4);
    float* dinv    = (float*)alloc((size_t)N * 4);
    uint*  W1p     = (uint*)alloc((size_t)64 * 128 * 4);    // 32 KB packed W1
    uint*  hs_b    = (uint*)alloc((size_t)N * 64 * 4);      // 25.6 MB, [2][N][32]
    uint*  rh_b    = (uint*)alloc((size_t)N * 64 * 4);
    uint*  h2_b    = hs_b;  // hs_b dead after k_agg1; reuse

    k_p1hist<<<P1 + 32, 256, 0, stream>>>(dst, E, N, C, chunk, hist1, W1, W1p);
    k_p1scan<<<1, 1024, 0, stream>>>(hist1, C, cbase);
    k_p1fill<<<P1, 256, 0, stream>>>(src, dst, E, N, C, chunk, hist1, binned1);
    int g1 = min(768, ntiles);
    k_p2gemm1<<<C + g1, 256, 0, stream>>>(binned1, cbase, N, C, ssrc, rowptr, deg, dinv,
                                          W1p, x, hs_b, ntiles);
    int groups = (N + 31) / 32;
    k_agg1<<<groups * 8, 256, 0, stream>>>(hs_b, rowptr, deg, ssrc, dinv,
                                           (const float2*)b1, N, rh_b);
    k_gemm2<<<(N + 255) / 256, 256, 0, stream>>>(rh_b, W2, dinv, N, h2_b);
    k_agg2<<<(N + 3) / 4, 256, 0, stream>>>(h2_b, rowptr, deg, ssrc, dinv, b2, N,
                                            (float2*)d_out);
}